// Round 1
// baseline (354.958 us; speedup 1.0000x reference)
//
#include <hip/hip_runtime.h>

#define WINDOW 13
#define NTOT   53248          // 13*64*64 voxels per (b,c)
#define WPB    4              // windows per block
#define VT     (WPB*WINDOW)   // 52 voxels per tile
#define NQ     (VT/4)         // 13 float4 quads per row
#define ROWS   80             // 8 q-rows + 8 k-rows + 64 v-rows

__global__ __launch_bounds__(256, 2)
void attn_win13_kernel(const float* __restrict__ x,
                       const float* __restrict__ wq, const float* __restrict__ bq,
                       const float* __restrict__ wk, const float* __restrict__ bk,
                       const float* __restrict__ wv, const float* __restrict__ bv,
                       float* __restrict__ out)
{
    // LDS: 5120 + 80 + 3328 + 4160 + 676 = 13364 floats = 53.5 KB -> 2 blocks/CU
    __shared__ float wall[ROWS * 64];       // rows 0..7 wq, 8..15 wk, 16..79 wv
    __shared__ float ball[ROWS];
    __shared__ float xs[64 * VT];           // x tile, stride 52 (float4-aligned)
    __shared__ float qkv[ROWS * VT];        // q/k/v tile, stride 52
    __shared__ float att[WPB * WINDOW * WINDOW]; // 4*169 = 676

    const int tid = threadIdx.x;
    const int b  = blockIdx.y;
    const int v0 = blockIdx.x * VT;         // tile start in flattened N (13*4 = 52)

    // ---- phase 1: stage weights + x tile ----
    for (int i = tid; i < 8 * 64; i += 256) {
        wall[i]          = wq[i];
        wall[8 * 64 + i] = wk[i];
    }
    for (int i = tid; i < 64 * 64; i += 256) wall[16 * 64 + i] = wv[i];
    if (tid < 8)       { ball[tid] = bq[tid]; ball[8 + tid] = bk[tid]; }
    else if (tid < 72) { ball[16 + (tid - 8)] = bv[tid - 8]; }

    // x tile: 64 rows x 52 floats; 52 floats = 208 B per row, tile offset 208B*blockIdx.x
    // -> every float4 below is 16B-aligned.
    for (int f = tid; f < 64 * NQ; f += 256) {
        int c = f / NQ, q = f % NQ;
        const float4 xv = *(const float4*)(x + (size_t)(b * 64 + c) * NTOT + v0 + q * 4);
        *(float4*)(xs + c * VT + q * 4) = xv;
    }
    __syncthreads();

    // ---- phase 2: qkv = W @ x_tile + bias  (80 x 52, K=64) ----
    for (int f = tid; f < ROWS * NQ; f += 256) {
        int r = f / NQ, q = f % NQ;
        float bias = ball[r];
        float4 acc; acc.x = bias; acc.y = bias; acc.z = bias; acc.w = bias;
        const float* wrow = wall + r * 64;
#pragma unroll 8
        for (int ch = 0; ch < 64; ++ch) {
            float w = wrow[ch];
            float4 xv = *(const float4*)(xs + ch * VT + q * 4);
            acc.x += w * xv.x; acc.y += w * xv.y; acc.z += w * xv.z; acc.w += w * xv.w;
        }
        *(float4*)(qkv + r * VT + q * 4) = acc;
    }
    __syncthreads();

    // ---- phase 3a: scores[w][i][j] = sum_o q[o][w,i] * k[o][w,j] ----
    for (int f = tid; f < WPB * 169; f += 256) {
        int w = f / 169, rem = f % 169;
        int i = rem / 13, j = rem % 13;
        float s = 0.f;
#pragma unroll
        for (int o = 0; o < 8; ++o)
            s += qkv[o * VT + w * 13 + i] * qkv[(8 + o) * VT + w * 13 + j];
        att[f] = s;
    }
    __syncthreads();

    // ---- phase 3b: softmax over j, one thread per (window,row) ----
    if (tid < WPB * WINDOW) {
        float* row = att + tid * 13;
        float m = row[0];
#pragma unroll
        for (int j = 1; j < 13; ++j) m = fmaxf(m, row[j]);
        float e[13]; float sum = 0.f;
#pragma unroll
        for (int j = 0; j < 13; ++j) { e[j] = __expf(row[j] - m); sum += e[j]; }
        float inv = 1.f / sum;
#pragma unroll
        for (int j = 0; j < 13; ++j) row[j] = e[j] * inv;
    }
    __syncthreads();

    // ---- phase 4: out[c][w,i] = sum_j v[c][w,j] * att[w][i][j], direct to global ----
    for (int f = tid; f < 64 * VT; f += 256) {
        int c = f / VT, v = f % VT;
        int w = v / 13, i = v % 13;
        const float* vrow = qkv + (16 + c) * VT + w * 13;
        const float* arow = att + (w * 13 + i) * 13;
        float acc = 0.f;
#pragma unroll
        for (int j = 0; j < 13; ++j) acc += vrow[j] * arow[j];
        out[(size_t)(b * 64 + c) * NTOT + v0 + v] = acc;
    }
}

extern "C" void kernel_launch(void* const* d_in, const int* in_sizes, int n_in,
                              void* d_out, int out_size, void* d_ws, size_t ws_size,
                              hipStream_t stream) {
    const float* x  = (const float*)d_in[0];
    const float* wq = (const float*)d_in[1];
    const float* bq = (const float*)d_in[2];
    const float* wk = (const float*)d_in[3];
    const float* bk = (const float*)d_in[4];
    const float* wv = (const float*)d_in[5];
    const float* bv = (const float*)d_in[6];
    float* out = (float*)d_out;

    dim3 grid(NTOT / VT, 8);   // 1024 tiles x 8 batches
    dim3 block(256);
    attn_win13_kernel<<<grid, block, 0, stream>>>(x, wq, bq, wk, bk, wv, bv, out);
}